// Round 6
// baseline (621.222 us; speedup 1.0000x reference)
//
#include <hip/hip_runtime.h>

// ---- problem constants ----
#define H_     8
#define DM_    1024
#define NQKV_  4096
#define ROWS_  16384          // SLEN*BSZ = 256*64
#define PAIRS_ 512            // BSZ*H
#define SCALE_ 0.08838834764831845f
#define LN_EPS_ 1e-5f

typedef __attribute__((ext_vector_type(8))) short short8;   // 8 bf16 (4 VGPRs)
typedef __attribute__((ext_vector_type(4))) float floatx4;  // MFMA accumulator

__device__ __forceinline__ float b2f(unsigned short u) {
  union { unsigned int i; float f; } v; v.i = ((unsigned int)u) << 16; return v.f;
}
__device__ __forceinline__ unsigned short f2b(float f) {
  union { unsigned int i; float f; } v; v.f = f;
  unsigned int b = v.i;
  b += 0x7FFFu + ((b >> 16) & 1u);   // round-to-nearest-even
  return (unsigned short)(b >> 16);
}

// ---- async stage with XOR bank swizzle ----
// LDS tile [128 rows][8 groups of 8 bf16]. LDS group j of row r holds global
// column-group (j ^ (r&7)). Dest stays lane-contiguous (global_load_lds
// constraint); source XOR keeps reads within the same 128B row segment.
__device__ __forceinline__ void stage_async(const unsigned short* __restrict__ g,
                                            size_t ld, unsigned short* s, int tid) {
#pragma unroll
  for (int p = 0; p < 4; ++p) {
    int idx = p * 256 + tid;
    int r = idx >> 3, j = idx & 7;
    int cg = j ^ (r & 7);
    __builtin_amdgcn_global_load_lds(
        (const __attribute__((address_space(1))) unsigned int*)(g + (size_t)r * ld + cg * 8),
        (__attribute__((address_space(3))) unsigned int*)(s + (size_t)idx * 8),
        16, 0, 0);
  }
}
// fragment read: global col-group cg of row -> LDS group cg ^ (row&7).
__device__ __forceinline__ short8 lds_frag(const unsigned short* s, int row, int cg) {
  return *(const short8*)(s + row * 64 + ((cg ^ (row & 7)) << 3));
}

// =====================================================================
// K0: fused fp32 -> bf16 convert of h, Wqkv, Wo (8 elems/thread)
// =====================================================================
__global__ __launch_bounds__(256) void cvt_all(const float* __restrict__ h,
                                               const float* __restrict__ wq,
                                               const float* __restrict__ wo,
                                               unsigned short* __restrict__ hb,
                                               unsigned short* __restrict__ wqb,
                                               unsigned short* __restrict__ wob) {
  int i = blockIdx.x * 256 + threadIdx.x;
  const float* src; unsigned short* dst; int off;
  if (i < 2097152)      { src = h;  dst = hb;  off = i; }
  else if (i < 2621440) { src = wq; dst = wqb; off = i - 2097152; }
  else                  { src = wo; dst = wob; off = i - 2621440; }
  const float4* s4 = (const float4*)(src + (size_t)off * 8);
  float4 v0 = s4[0], v1 = s4[1];
  union { short8 v; unsigned short u[8]; } pk;
  pk.u[0] = f2b(v0.x); pk.u[1] = f2b(v0.y); pk.u[2] = f2b(v0.z); pk.u[3] = f2b(v0.w);
  pk.u[4] = f2b(v1.x); pk.u[5] = f2b(v1.y); pk.u[6] = f2b(v1.z); pk.u[7] = f2b(v1.w);
  *(short8*)(dst + (size_t)off * 8) = pk.v;
}

// =====================================================================
// K1: qkv gemm + fused phi + coalesced scatter epilogues.
//   part<3 (q,k1,k2): phi-normalize in regs, transpose-stage through LDS
//     T[128][136], write full 256B P-rows with 16B/lane stores.
//   part==3 (v): b-major M-tiles; LDS transpose then coalesced Vt stores.
// =====================================================================
__global__ __launch_bounds__(256, 4) void qkv_gemm(const unsigned short* __restrict__ A,
                                                   const unsigned short* __restrict__ B,
                                                   unsigned short* __restrict__ QKV) {
  // union: staging 2x(128x64) shorts = 16384; transpose [128][136] = 17408
  __shared__ alignas(16) unsigned short Sh[17408];
  unsigned short* As = Sh;
  unsigned short* Bs = Sh + 8192;
  int tid = threadIdx.x;
  int lane = tid & 63, wid = tid >> 6;
  int wm = wid >> 1, wn = wid & 1;
  int quad = lane >> 4, l16 = lane & 15;
  int m0 = blockIdx.y * 128, n0 = blockIdx.x * 128;
  int hh = n0 >> 9, part = (n0 >> 7) & 3;
  int bb = blockIdx.y & 63, lhalf = blockIdx.y >> 6;   // b-major mapping (part==3)

  const unsigned short* Ab;
  size_t lda;
  if (part == 3) { Ab = A + ((size_t)(lhalf * 128) * 64 + bb) * DM_; lda = (size_t)64 * DM_; }
  else           { Ab = A + (size_t)m0 * DM_;                        lda = DM_; }
  const unsigned short* Bb = B + (size_t)n0 * DM_;

  floatx4 acc[4][4];
#pragma unroll
  for (int i = 0; i < 4; ++i)
#pragma unroll
    for (int j = 0; j < 4; ++j)
#pragma unroll
      for (int r = 0; r < 4; ++r) acc[i][j][r] = 0.f;

  for (int kt = 0; kt < DM_; kt += 64) {
    stage_async(Ab + kt, lda, As, tid);
    stage_async(Bb + kt, DM_, Bs, tid);
    __syncthreads();
#pragma unroll
    for (int kk = 0; kk < 2; ++kk) {
      short8 af[4], bfv[4];
#pragma unroll
      for (int mt = 0; mt < 4; ++mt)
        af[mt] = lds_frag(As, wm * 64 + mt * 16 + l16, kk * 4 + quad);
#pragma unroll
      for (int nt = 0; nt < 4; ++nt)
        bfv[nt] = lds_frag(Bs, wn * 64 + nt * 16 + l16, kk * 4 + quad);
#pragma unroll
      for (int mt = 0; mt < 4; ++mt)
#pragma unroll
        for (int nt = 0; nt < 4; ++nt)
          acc[mt][nt] = __builtin_amdgcn_mfma_f32_16x16x32_bf16(af[mt], bfv[nt], acc[mt][nt], 0, 0, 0);
    }
    __syncthreads();
  }

  if (part < 3) {
    unsigned short* P = QKV + (size_t)part * 16777216;
    float rsum[4][4];
#pragma unroll
    for (int mt = 0; mt < 4; ++mt)
#pragma unroll
      for (int r = 0; r < 4; ++r) rsum[mt][r] = 0.f;
#pragma unroll
    for (int mt = 0; mt < 4; ++mt)
#pragma unroll
      for (int nt = 0; nt < 4; ++nt)
#pragma unroll
        for (int r = 0; r < 4; ++r) {
          float x = acc[mt][nt][r];
          float f = x > 0.f ? x + 1.f : __expf(x);   // elu(x)+1
          acc[mt][nt][r] = f;
          rsum[mt][r] += f;
        }
#pragma unroll
    for (int off = 1; off < 16; off <<= 1)
#pragma unroll
      for (int mt = 0; mt < 4; ++mt)
#pragma unroll
        for (int r = 0; r < 4; ++r)
          rsum[mt][r] += __shfl_xor(rsum[mt][r], off);
    float* red = (float*)Sh;
    if (l16 == 0) {
#pragma unroll
      for (int mt = 0; mt < 4; ++mt)
#pragma unroll
        for (int r = 0; r < 4; ++r)
          red[wn * 128 + wm * 64 + mt * 16 + quad * 4 + r] = rsum[mt][r];
    }
    __syncthreads();
    float inv[4][4];
#pragma unroll
    for (int mt = 0; mt < 4; ++mt)
#pragma unroll
      for (int r = 0; r < 4; ++r) {
        int rl = wm * 64 + mt * 16 + quad * 4 + r;
        inv[mt][r] = 1.f / (red[rl] + red[128 + rl]);
      }
    __syncthreads();          // red reads done before T overwrites Sh
    // transpose-stage normalized phi values: T[rl][136] (2-way max on writes)
#pragma unroll
    for (int mt = 0; mt < 4; ++mt)
#pragma unroll
      for (int nt = 0; nt < 4; ++nt)
#pragma unroll
        for (int r = 0; r < 4; ++r) {
          int rl = wm * 64 + mt * 16 + quad * 4 + r;
          int d = wn * 64 + nt * 16 + l16;
          Sh[rl * 136 + d] = f2b(acc[mt][nt][r] * inv[mt][r]);
        }
    __syncthreads();
    // coalesced out: 2 threads per row, 128B each -> full 64B lines
    int row = tid >> 1, halfc = tid & 1;
    int grow = m0 + row;
    int l = grow >> 6, bidx = grow & 63;
    size_t gbase = ((size_t)((bidx * 8 + hh) * 256 + l)) * 128 + halfc * 64;
    const unsigned short* trow = Sh + row * 136 + halfc * 64;
#pragma unroll
    for (int j = 0; j < 8; ++j)
      *(short8*)(P + gbase + j * 8) = *(const short8*)(trow + j * 8);
  } else {
    // transpose via LDS: T[d][136] <- C[l][d], then coalesced Vt stores
    unsigned short* T = Sh;
#pragma unroll
    for (int mt = 0; mt < 4; ++mt)
#pragma unroll
      for (int nt = 0; nt < 4; ++nt)
#pragma unroll
        for (int r = 0; r < 4; ++r) {
          int l = wm * 64 + mt * 16 + quad * 4 + r;
          int d = wn * 64 + nt * 16 + l16;
          T[d * 136 + l] = f2b(acc[mt][nt][r]);
        }
    __syncthreads();
    unsigned short* Vt = QKV + (size_t)3 * 16777216;
    int d = tid >> 1, lb = (tid & 1) * 64;
    size_t gbase = ((size_t)((bb * 8 + hh) * 128 + d)) * 256 + lhalf * 128 + lb;
    const unsigned short* trow = T + d * 136 + lb;
#pragma unroll
    for (int j = 0; j < 8; ++j)
      *(short8*)(Vt + gbase + j * 8) = *(const short8*)(trow + j * 8);
  }
}

// =====================================================================
// K2: fused attention (scores + PV), no S materialization.
//   grid (2, 512): blockIdx.x = t-half (ty), blockIdx.y = pair p.
//   Per s-chunk (sc <= ty): phase A computes combined masked scores
//   Sc[128 t][128 s] via MFMA into regs, writes to swizzled LDS (bf16);
//   phase B does O += Sc @ V chunk.  Epilogue scales and scatters to LO.
//   LDS: Qs+K1s+K2s (48K) + Sc[2] (32K) = 80K -> 2 blocks/CU.
// =====================================================================
__global__ __launch_bounds__(256, 2) void attn_kernel(const unsigned short* __restrict__ QKV,
                                                      const float* __restrict__ pi0,
                                                      unsigned short* __restrict__ LO) {
  __shared__ alignas(16) unsigned short Qs[8192], K1s[8192], K2s[8192], Scs[2][8192];
  int ty = blockIdx.x;              // t-half
  int p  = blockIdx.y;
  int b = p >> 3, hh = p & 7;
  int t0 = ty * 128;
  int tid = threadIdx.x;
  int lane = tid & 63, wid = tid >> 6;
  int wm = wid >> 1, wn = wid & 1;
  int quad = lane >> 4, l16 = lane & 15;

  const unsigned short* Qb  = QKV + (size_t)p * 32768 + (size_t)t0 * 128;
  const unsigned short* K1g = QKV + 16777216     + (size_t)p * 32768;
  const unsigned short* K2g = QKV + 2 * 16777216 + (size_t)p * 32768;
  const unsigned short* Vg  = QKV + (size_t)3 * 16777216 + (size_t)p * 32768;

  floatx4 oacc[4][4];
#pragma unroll
  for (int i = 0; i < 4; ++i)
#pragma unroll
    for (int j = 0; j < 4; ++j)
#pragma unroll
      for (int r = 0; r < 4; ++r) oacc[i][j][r] = 0.f;

  for (int sc = 0; sc <= ty; ++sc) {
    // ---- phase A: combined scores for s-chunk sc ----
    floatx4 acc1[4][4], acc2[4][4];
#pragma unroll
    for (int i = 0; i < 4; ++i)
#pragma unroll
      for (int j = 0; j < 4; ++j)
#pragma unroll
        for (int r = 0; r < 4; ++r) { acc1[i][j][r] = 0.f; acc2[i][j][r] = 0.f; }

    for (int kt = 0; kt < 128; kt += 64) {
      stage_async(Qb + kt, 128, Qs, tid);
      stage_async(K1g + (size_t)sc * 16384 + kt, 128, K1s, tid);
      stage_async(K2g + (size_t)sc * 16384 + kt, 128, K2s, tid);
      __syncthreads();
#pragma unroll
      for (int kk = 0; kk < 2; ++kk) {
        short8 af[4], b1[4], b2v[4];
#pragma unroll
        for (int mt = 0; mt < 4; ++mt)
          af[mt] = lds_frag(Qs, wm * 64 + mt * 16 + l16, kk * 4 + quad);
#pragma unroll
        for (int nt = 0; nt < 4; ++nt) {
          b1[nt]  = lds_frag(K1s, wn * 64 + nt * 16 + l16, kk * 4 + quad);
          b2v[nt] = lds_frag(K2s, wn * 64 + nt * 16 + l16, kk * 4 + quad);
        }
#pragma unroll
        for (int mt = 0; mt < 4; ++mt)
#pragma unroll
          for (int nt = 0; nt < 4; ++nt) {
            acc1[mt][nt] = __builtin_amdgcn_mfma_f32_16x16x32_bf16(af[mt], b1[nt],  acc1[mt][nt], 0, 0, 0);
            acc2[mt][nt] = __builtin_amdgcn_mfma_f32_16x16x32_bf16(af[mt], b2v[nt], acc2[mt][nt], 0, 0, 0);
          }
      }
      __syncthreads();
    }
    // ---- combine with pi, mask, write Sc to swizzled LDS ----
#pragma unroll
    for (int mt = 0; mt < 4; ++mt)
#pragma unroll
      for (int r = 0; r < 4; ++r) {
        int tl = wm * 64 + mt * 16 + quad * 4 + r;
        float pv = pi0[hh * 256 + t0 + tl];
        pv = fminf(fmaxf(pv, 0.f), 1.f);
#pragma unroll
        for (int nt = 0; nt < 4; ++nt) {
          int sl = wn * 64 + nt * 16 + l16;
          float v = pv * acc1[mt][nt][r] + (1.f - pv) * acc2[mt][nt][r];
          if (sc == ty && sl > tl) v = 0.f;
          int col = sl & 63, half = sl >> 6;
          Scs[half][tl * 64 + ((((col >> 3) ^ (tl & 7))) << 3) + (col & 7)] = f2b(v);
        }
      }
    __syncthreads();
    // ---- phase B: O += Sc @ V chunk (K=128 over s, two 64-sub-chunks) ----
#pragma unroll
    for (int kc = 0; kc < 2; ++kc) {
      stage_async(Vg + sc * 128 + kc * 64, 256, K1s, tid);   // Vs aliases K1s
      __syncthreads();
#pragma unroll
      for (int kk = 0; kk < 2; ++kk) {
        short8 af[4], bfv[4];
#pragma unroll
        for (int mt = 0; mt < 4; ++mt)
          af[mt] = lds_frag(Scs[kc], wm * 64 + mt * 16 + l16, kk * 4 + quad);
#pragma unroll
        for (int nt = 0; nt < 4; ++nt)
          bfv[nt] = lds_frag(K1s, wn * 64 + nt * 16 + l16, kk * 4 + quad);
#pragma unroll
        for (int mt = 0; mt < 4; ++mt)
#pragma unroll
          for (int nt = 0; nt < 4; ++nt)
            oacc[mt][nt] = __builtin_amdgcn_mfma_f32_16x16x32_bf16(af[mt], bfv[nt], oacc[mt][nt], 0, 0, 0);
      }
      __syncthreads();
    }
  }
  // ---- epilogue: LO[(t*64+b)*1024 + hh*128 + d] ----
#pragma unroll
  for (int mt = 0; mt < 4; ++mt)
#pragma unroll
    for (int nt = 0; nt < 4; ++nt)
#pragma unroll
      for (int r = 0; r < 4; ++r) {
        int t = t0 + wm * 64 + mt * 16 + quad * 4 + r;
        int d = wn * 64 + nt * 16 + l16;
        LO[((size_t)t * 64 + b) * 1024 + hh * 128 + d] = f2b(SCALE_ * oacc[mt][nt][r]);
      }
}

// =====================================================================
// K5: X[row,m] = h[row,m] + sum_n LO[row,n]*Wo[m,n]  (X fp32 = d_out)
// =====================================================================
__global__ __launch_bounds__(256, 4) void wo_gemm(const unsigned short* __restrict__ A,
                                                  const unsigned short* __restrict__ B,
                                                  const float* __restrict__ hin,
                                                  float* __restrict__ X) {
  __shared__ alignas(16) unsigned short As[128 * 64], Bs[128 * 64];
  int tid = threadIdx.x;
  int lane = tid & 63, wid = tid >> 6;
  int wm = wid >> 1, wn = wid & 1;
  int quad = lane >> 4, l16 = lane & 15;
  int m0 = blockIdx.y * 128, n0 = blockIdx.x * 128;
  const unsigned short* Ab = A + (size_t)m0 * DM_;
  const unsigned short* Bb = B + (size_t)n0 * DM_;

  floatx4 acc[4][4];
#pragma unroll
  for (int i = 0; i < 4; ++i)
#pragma unroll
    for (int j = 0; j < 4; ++j)
#pragma unroll
      for (int r = 0; r < 4; ++r) acc[i][j][r] = 0.f;

  for (int kt = 0; kt < DM_; kt += 64) {
    stage_async(Ab + kt, DM_, As, tid);
    stage_async(Bb + kt, DM_, Bs, tid);
    __syncthreads();
#pragma unroll
    for (int kk = 0; kk < 2; ++kk) {
      short8 af[4], bfv[4];
#pragma unroll
      for (int mt = 0; mt < 4; ++mt)
        af[mt] = lds_frag(As, wm * 64 + mt * 16 + l16, kk * 4 + quad);
#pragma unroll
      for (int nt = 0; nt < 4; ++nt)
        bfv[nt] = lds_frag(Bs, wn * 64 + nt * 16 + l16, kk * 4 + quad);
#pragma unroll
      for (int mt = 0; mt < 4; ++mt)
#pragma unroll
        for (int nt = 0; nt < 4; ++nt)
          acc[mt][nt] = __builtin_amdgcn_mfma_f32_16x16x32_bf16(af[mt], bfv[nt], acc[mt][nt], 0, 0, 0);
    }
    __syncthreads();
  }
#pragma unroll
  for (int mt = 0; mt < 4; ++mt)
#pragma unroll
    for (int nt = 0; nt < 4; ++nt)
#pragma unroll
      for (int r = 0; r < 4; ++r) {
        int row = m0 + wm * 64 + mt * 16 + quad * 4 + r;
        int col = n0 + wn * 64 + nt * 16 + l16;
        size_t idx = (size_t)row * DM_ + col;
        X[idx] = acc[mt][nt][r] + hin[idx];
      }
}

// =====================================================================
// K6: LayerNorm in-place on X (= d_out, fp32).  One block per row.
// =====================================================================
__global__ __launch_bounds__(256) void ln_kernel(float* __restrict__ X,
                                                 const float* __restrict__ gamma,
                                                 const float* __restrict__ beta) {
  int row = blockIdx.x;
  int tid = threadIdx.x;
  float* x = X + (size_t)row * DM_;
  float4 v = *(const float4*)(x + tid * 4);
  float s  = v.x + v.y + v.z + v.w;
  float ss = v.x * v.x + v.y * v.y + v.z * v.z + v.w * v.w;
#pragma unroll
  for (int off = 32; off; off >>= 1) {
    s  += __shfl_down(s, off);
    ss += __shfl_down(ss, off);
  }
  __shared__ float rs[4], rss[4];
  int wv = tid >> 6, lane = tid & 63;
  if (lane == 0) { rs[wv] = s; rss[wv] = ss; }
  __syncthreads();
  float St  = rs[0] + rs[1] + rs[2] + rs[3];
  float SSt = rss[0] + rss[1] + rss[2] + rss[3];
  float mu = St * (1.f / DM_);
  float var = SSt * (1.f / DM_) - mu * mu;
  float rstd = rsqrtf(var + LN_EPS_);
  float4 o;
#pragma unroll
  for (int j = 0; j < 4; ++j) {
    int c = tid * 4 + j;
    (&o.x)[j] = gamma[c] * ((&v.x)[j] - mu) * rstd + beta[c];
  }
  *(float4*)(x + tid * 4) = o;
}

// =====================================================================
extern "C" void kernel_launch(void* const* d_in, const int* in_sizes, int n_in,
                              void* d_out, int out_size, void* d_ws, size_t ws_size,
                              hipStream_t stream) {
  const float* h     = (const float*)d_in[0];
  const float* Wqkv  = (const float*)d_in[1];
  const float* Wo    = (const float*)d_in[2];
  const float* pi0   = (const float*)d_in[3];
  const float* gamma = (const float*)d_in[4];
  const float* beta  = (const float*)d_in[5];
  char* ws = (char*)d_ws;

  // ws layout (peak 170 MB, all bf16 unless noted):
  //   [0,32M)    Q(phi)   [32,64) K1   [64,96) K2   [96,128) Vt
  //   [128,160)  hb (bf16 h; dead after qkv) -> reused as LO [16384][1024]
  //   [160,168)  Wqkvb    [168,170) Wob
  // X (fp32 residual) = d_out; LN in-place.  No S buffer (attn fused).
  unsigned short* QKV   = (unsigned short*)ws;
  unsigned short* hb    = (unsigned short*)(ws + 134217728ull);
  unsigned short* LO    = (unsigned short*)(ws + 134217728ull);
  unsigned short* Wqkvb = (unsigned short*)(ws + 167772160ull);
  unsigned short* Wob   = (unsigned short*)(ws + 176160768ull);
  float* X = (float*)d_out;

  dim3 blk(256);
  cvt_all<<<dim3(10752), blk, 0, stream>>>(h, Wqkv, Wo, hb, Wqkvb, Wob);
  qkv_gemm<<<dim3(NQKV_ / 128, ROWS_ / 128, 1), blk, 0, stream>>>(hb, Wqkvb, QKV);
  attn_kernel<<<dim3(2, PAIRS_), blk, 0, stream>>>(QKV, pi0, LO);
  wo_gemm<<<dim3(DM_ / 128, ROWS_ / 128, 1), blk, 0, stream>>>(LO, Wob, h, X);
  ln_kernel<<<dim3(ROWS_, 1, 1), blk, 0, stream>>>(X, gamma, beta);
}

// Round 7
// 478.842 us; speedup vs baseline: 1.2973x; 1.2973x over previous
//
#include <hip/hip_runtime.h>

// ---- problem constants ----
#define H_     8
#define DM_    1024
#define NQKV_  4096
#define ROWS_  16384          // SLEN*BSZ = 256*64
#define PAIRS_ 512            // BSZ*H
#define SCALE_ 0.08838834764831845f
#define LN_EPS_ 1e-5f

typedef __attribute__((ext_vector_type(8))) short short8;   // 8 bf16 (4 VGPRs)
typedef __attribute__((ext_vector_type(4))) float floatx4;  // MFMA accumulator

__device__ __forceinline__ float b2f(unsigned short u) {
  union { unsigned int i; float f; } v; v.i = ((unsigned int)u) << 16; return v.f;
}
__device__ __forceinline__ unsigned short f2b(float f) {
  union { unsigned int i; float f; } v; v.f = f;
  unsigned int b = v.i;
  b += 0x7FFFu + ((b >> 16) & 1u);   // round-to-nearest-even
  return (unsigned short)(b >> 16);
}

// ---- async stage with XOR bank swizzle ----
// LDS tile [128 rows][8 groups of 8 bf16]. LDS group j of row r holds global
// column-group (j ^ (r&7)). Dest stays lane-contiguous (global_load_lds
// constraint); source XOR keeps reads within the same 128B row segment.
__device__ __forceinline__ void stage_async(const unsigned short* __restrict__ g,
                                            size_t ld, unsigned short* s, int tid) {
#pragma unroll
  for (int p = 0; p < 4; ++p) {
    int idx = p * 256 + tid;
    int r = idx >> 3, j = idx & 7;
    int cg = j ^ (r & 7);
    __builtin_amdgcn_global_load_lds(
        (const __attribute__((address_space(1))) unsigned int*)(g + (size_t)r * ld + cg * 8),
        (__attribute__((address_space(3))) unsigned int*)(s + (size_t)idx * 8),
        16, 0, 0);
  }
}
// fragment read: global col-group cg of row -> LDS group cg ^ (row&7).
__device__ __forceinline__ short8 lds_frag(const unsigned short* s, int row, int cg) {
  return *(const short8*)(s + row * 64 + ((cg ^ (row & 7)) << 3));
}

// =====================================================================
// K0: fused fp32 -> bf16 convert of h, Wqkv, Wo (8 elems/thread)
// =====================================================================
__global__ __launch_bounds__(256) void cvt_all(const float* __restrict__ h,
                                               const float* __restrict__ wq,
                                               const float* __restrict__ wo,
                                               unsigned short* __restrict__ hb,
                                               unsigned short* __restrict__ wqb,
                                               unsigned short* __restrict__ wob) {
  int i = blockIdx.x * 256 + threadIdx.x;
  const float* src; unsigned short* dst; int off;
  if (i < 2097152)      { src = h;  dst = hb;  off = i; }
  else if (i < 2621440) { src = wq; dst = wqb; off = i - 2097152; }
  else                  { src = wo; dst = wob; off = i - 2621440; }
  const float4* s4 = (const float4*)(src + (size_t)off * 8);
  float4 v0 = s4[0], v1 = s4[1];
  union { short8 v; unsigned short u[8]; } pk;
  pk.u[0] = f2b(v0.x); pk.u[1] = f2b(v0.y); pk.u[2] = f2b(v0.z); pk.u[3] = f2b(v0.w);
  pk.u[4] = f2b(v1.x); pk.u[5] = f2b(v1.y); pk.u[6] = f2b(v1.z); pk.u[7] = f2b(v1.w);
  *(short8*)(dst + (size_t)off * 8) = pk.v;
}

// =====================================================================
// K1: qkv gemm + fused phi + FULL-LINE scatter epilogues.
//   All stores: stage tile in LDS T[128][136], then store with
//   lane mapping (chunk = lane&15, row = j*16 + (tid>>4)) -> each wave
//   instruction covers 4 x 256B aligned segments (full 64B sectors).
// =====================================================================
__global__ __launch_bounds__(256, 4) void qkv_gemm(const unsigned short* __restrict__ A,
                                                   const unsigned short* __restrict__ B,
                                                   unsigned short* __restrict__ QKV) {
  // union: staging 2x(128x64) shorts = 16384; transpose [128][136] = 17408
  __shared__ alignas(16) unsigned short Sh[17408];
  unsigned short* As = Sh;
  unsigned short* Bs = Sh + 8192;
  int tid = threadIdx.x;
  int lane = tid & 63, wid = tid >> 6;
  int wm = wid >> 1, wn = wid & 1;
  int quad = lane >> 4, l16 = lane & 15;
  int m0 = blockIdx.y * 128, n0 = blockIdx.x * 128;
  int hh = n0 >> 9, part = (n0 >> 7) & 3;
  int bb = blockIdx.y & 63, lhalf = blockIdx.y >> 6;   // b-major mapping (part==3)

  const unsigned short* Ab;
  size_t lda;
  if (part == 3) { Ab = A + ((size_t)(lhalf * 128) * 64 + bb) * DM_; lda = (size_t)64 * DM_; }
  else           { Ab = A + (size_t)m0 * DM_;                        lda = DM_; }
  const unsigned short* Bb = B + (size_t)n0 * DM_;

  floatx4 acc[4][4];
#pragma unroll
  for (int i = 0; i < 4; ++i)
#pragma unroll
    for (int j = 0; j < 4; ++j)
#pragma unroll
      for (int r = 0; r < 4; ++r) acc[i][j][r] = 0.f;

  for (int kt = 0; kt < DM_; kt += 64) {
    stage_async(Ab + kt, lda, As, tid);
    stage_async(Bb + kt, DM_, Bs, tid);
    __syncthreads();
#pragma unroll
    for (int kk = 0; kk < 2; ++kk) {
      short8 af[4], bfv[4];
#pragma unroll
      for (int mt = 0; mt < 4; ++mt)
        af[mt] = lds_frag(As, wm * 64 + mt * 16 + l16, kk * 4 + quad);
#pragma unroll
      for (int nt = 0; nt < 4; ++nt)
        bfv[nt] = lds_frag(Bs, wn * 64 + nt * 16 + l16, kk * 4 + quad);
#pragma unroll
      for (int mt = 0; mt < 4; ++mt)
#pragma unroll
        for (int nt = 0; nt < 4; ++nt)
          acc[mt][nt] = __builtin_amdgcn_mfma_f32_16x16x32_bf16(af[mt], bfv[nt], acc[mt][nt], 0, 0, 0);
    }
    __syncthreads();
  }

  int c = tid & 15, g = tid >> 4;     // full-line store mapping
  if (part < 3) {
    unsigned short* P = QKV + (size_t)part * 16777216;
    float rsum[4][4];
#pragma unroll
    for (int mt = 0; mt < 4; ++mt)
#pragma unroll
      for (int r = 0; r < 4; ++r) rsum[mt][r] = 0.f;
#pragma unroll
    for (int mt = 0; mt < 4; ++mt)
#pragma unroll
      for (int nt = 0; nt < 4; ++nt)
#pragma unroll
        for (int r = 0; r < 4; ++r) {
          float x = acc[mt][nt][r];
          float f = x > 0.f ? x + 1.f : __expf(x);   // elu(x)+1
          acc[mt][nt][r] = f;
          rsum[mt][r] += f;
        }
#pragma unroll
    for (int off = 1; off < 16; off <<= 1)
#pragma unroll
      for (int mt = 0; mt < 4; ++mt)
#pragma unroll
        for (int r = 0; r < 4; ++r)
          rsum[mt][r] += __shfl_xor(rsum[mt][r], off);
    float* red = (float*)Sh;
    if (l16 == 0) {
#pragma unroll
      for (int mt = 0; mt < 4; ++mt)
#pragma unroll
        for (int r = 0; r < 4; ++r)
          red[wn * 128 + wm * 64 + mt * 16 + quad * 4 + r] = rsum[mt][r];
    }
    __syncthreads();
    float inv[4][4];
#pragma unroll
    for (int mt = 0; mt < 4; ++mt)
#pragma unroll
      for (int r = 0; r < 4; ++r) {
        int rl = wm * 64 + mt * 16 + quad * 4 + r;
        inv[mt][r] = 1.f / (red[rl] + red[128 + rl]);
      }
    __syncthreads();          // red reads done before T overwrites Sh
    // stage normalized phi values: T[rl][136]
#pragma unroll
    for (int mt = 0; mt < 4; ++mt)
#pragma unroll
      for (int nt = 0; nt < 4; ++nt)
#pragma unroll
        for (int r = 0; r < 4; ++r) {
          int rl = wm * 64 + mt * 16 + quad * 4 + r;
          int d = wn * 64 + nt * 16 + l16;
          Sh[rl * 136 + d] = f2b(acc[mt][nt][r] * inv[mt][r]);
        }
    __syncthreads();
#pragma unroll
    for (int j = 0; j < 8; ++j) {
      int r = j * 16 + g;
      int grow = m0 + r;
      int l = grow >> 6, bidx = grow & 63;
      size_t gb = ((size_t)((bidx * 8 + hh) * 256 + l)) * 128 + c * 8;
      *(short8*)(P + gb) = *(const short8*)(Sh + r * 136 + c * 8);
    }
  } else {
    // transpose via LDS: T[d][136] <- C[l][d], coalesced full-line Vt stores
#pragma unroll
    for (int mt = 0; mt < 4; ++mt)
#pragma unroll
      for (int nt = 0; nt < 4; ++nt)
#pragma unroll
        for (int r = 0; r < 4; ++r) {
          int l = wm * 64 + mt * 16 + quad * 4 + r;
          int d = wn * 64 + nt * 16 + l16;
          Sh[d * 136 + l] = f2b(acc[mt][nt][r]);
        }
    __syncthreads();
    unsigned short* Vt = QKV + (size_t)3 * 16777216;
#pragma unroll
    for (int j = 0; j < 8; ++j) {
      int d = j * 16 + g;
      size_t gb = ((size_t)((bb * 8 + hh) * 128 + d)) * 256 + lhalf * 128 + c * 8;
      *(short8*)(Vt + gb) = *(const short8*)(Sh + d * 136 + c * 8);
    }
  }
}

// =====================================================================
// K3: combined masked scores.  grid (3, 1, 512); full-line S stores.
// =====================================================================
__global__ __launch_bounds__(256) void scores_kernel(const unsigned short* __restrict__ QKV,
                                                     const float* __restrict__ pi0,
                                                     unsigned short* __restrict__ S) {
  __shared__ alignas(16) unsigned short Sh[24576];   // As|Bs1|Bs2; reused as T[128][136]
  __shared__ float pis[128];
  unsigned short* As  = Sh;
  unsigned short* Bs1 = Sh + 8192;
  unsigned short* Bs2 = Sh + 16384;
  int p = blockIdx.z;
  int hh = p & 7;
  int tid = threadIdx.x;
  int lane = tid & 63, wid = tid >> 6;
  int wm = wid >> 1, wn = wid & 1;
  int quad = lane >> 4, l16 = lane & 15;
  int tix = blockIdx.x;
  int m0 = (tix >= 1) ? 128 : 0;
  int n0 = (tix == 2) ? 128 : 0;
  if (tid < 128) {
    float pv = pi0[hh * 256 + m0 + tid];
    pis[tid] = fminf(fmaxf(pv, 0.f), 1.f);
  }
  const unsigned short* Qb  = QKV + (size_t)p * 32768 + (size_t)m0 * 128;
  const unsigned short* K1b = QKV + 16777216     + (size_t)p * 32768 + (size_t)n0 * 128;
  const unsigned short* K2b = QKV + 2 * 16777216 + (size_t)p * 32768 + (size_t)n0 * 128;

  floatx4 acc1[4][4], acc2[4][4];
#pragma unroll
  for (int i = 0; i < 4; ++i)
#pragma unroll
    for (int j = 0; j < 4; ++j)
#pragma unroll
      for (int r = 0; r < 4; ++r) { acc1[i][j][r] = 0.f; acc2[i][j][r] = 0.f; }

  for (int kt = 0; kt < 128; kt += 64) {
    stage_async(Qb + kt, 128, As, tid);
    stage_async(K1b + kt, 128, Bs1, tid);
    stage_async(K2b + kt, 128, Bs2, tid);
    __syncthreads();
#pragma unroll
    for (int kk = 0; kk < 2; ++kk) {
      short8 af[4], b1[4], b2v[4];
#pragma unroll
      for (int mt = 0; mt < 4; ++mt)
        af[mt] = lds_frag(As, wm * 64 + mt * 16 + l16, kk * 4 + quad);
#pragma unroll
      for (int nt = 0; nt < 4; ++nt) {
        b1[nt]  = lds_frag(Bs1, wn * 64 + nt * 16 + l16, kk * 4 + quad);
        b2v[nt] = lds_frag(Bs2, wn * 64 + nt * 16 + l16, kk * 4 + quad);
      }
#pragma unroll
      for (int mt = 0; mt < 4; ++mt)
#pragma unroll
        for (int nt = 0; nt < 4; ++nt) {
          acc1[mt][nt] = __builtin_amdgcn_mfma_f32_16x16x32_bf16(af[mt], b1[nt],  acc1[mt][nt], 0, 0, 0);
          acc2[mt][nt] = __builtin_amdgcn_mfma_f32_16x16x32_bf16(af[mt], b2v[nt], acc2[mt][nt], 0, 0, 0);
        }
    }
    __syncthreads();
  }
  // combine + mask -> T[128][136]
#pragma unroll
  for (int mt = 0; mt < 4; ++mt)
#pragma unroll
    for (int nt = 0; nt < 4; ++nt)
#pragma unroll
      for (int r = 0; r < 4; ++r) {
        int tl = wm * 64 + mt * 16 + quad * 4 + r;
        int sl = wn * 64 + nt * 16 + l16;
        float pv = pis[tl];
        float v = (n0 + sl <= m0 + tl) ? (pv * acc1[mt][nt][r] + (1.f - pv) * acc2[mt][nt][r]) : 0.f;
        Sh[tl * 136 + sl] = f2b(v);
      }
  __syncthreads();
  int c = tid & 15, g = tid >> 4;
#pragma unroll
  for (int j = 0; j < 8; ++j) {
    int r = j * 16 + g;
    size_t gb = (size_t)p * 65536 + (size_t)(m0 + r) * 256 + n0 + c * 8;
    *(short8*)(S + gb) = *(const short8*)(Sh + r * 136 + c * 8);
  }
}

// =====================================================================
// K4: O = SCALE * S @ V -> LO; full-line stores.  grid (1,2,512)
// =====================================================================
__global__ __launch_bounds__(256, 4) void pv_kernel(const unsigned short* __restrict__ S,
                                                    const unsigned short* __restrict__ Vt,
                                                    unsigned short* __restrict__ LO) {
  __shared__ alignas(16) unsigned short Sh[17408];   // As|Bs; reused as T[128][136]
  unsigned short* As = Sh;
  unsigned short* Bs = Sh + 8192;
  int p = blockIdx.z;
  int b = p >> 3, hh = p & 7;
  int tid = threadIdx.x;
  int lane = tid & 63, wid = tid >> 6;
  int wm = wid >> 1, wn = wid & 1;
  int quad = lane >> 4, l16 = lane & 15;
  int m0 = blockIdx.y * 128;
  int kEnd = (blockIdx.y == 0) ? 128 : 256;   // rows t<128 only need s<128
  const unsigned short* Ab = S  + (size_t)p * 65536 + (size_t)m0 * 256;
  const unsigned short* Bb = Vt + (size_t)p * 32768;

  floatx4 acc[4][4];
#pragma unroll
  for (int i = 0; i < 4; ++i)
#pragma unroll
    for (int j = 0; j < 4; ++j)
#pragma unroll
      for (int r = 0; r < 4; ++r) acc[i][j][r] = 0.f;

  for (int kt = 0; kt < kEnd; kt += 64) {
    stage_async(Ab + kt, 256, As, tid);
    stage_async(Bb + kt, 256, Bs, tid);
    __syncthreads();
#pragma unroll
    for (int kk = 0; kk < 2; ++kk) {
      short8 af[4], bfv[4];
#pragma unroll
      for (int mt = 0; mt < 4; ++mt)
        af[mt] = lds_frag(As, wm * 64 + mt * 16 + l16, kk * 4 + quad);
#pragma unroll
      for (int nt = 0; nt < 4; ++nt)
        bfv[nt] = lds_frag(Bs, wn * 64 + nt * 16 + l16, kk * 4 + quad);
#pragma unroll
      for (int mt = 0; mt < 4; ++mt)
#pragma unroll
        for (int nt = 0; nt < 4; ++nt)
          acc[mt][nt] = __builtin_amdgcn_mfma_f32_16x16x32_bf16(af[mt], bfv[nt], acc[mt][nt], 0, 0, 0);
    }
    __syncthreads();
  }
  // stage scaled O into T[128][136]
#pragma unroll
  for (int mt = 0; mt < 4; ++mt)
#pragma unroll
    for (int nt = 0; nt < 4; ++nt)
#pragma unroll
      for (int r = 0; r < 4; ++r) {
        int tl = wm * 64 + mt * 16 + quad * 4 + r;
        int d = wn * 64 + nt * 16 + l16;
        Sh[tl * 136 + d] = f2b(SCALE_ * acc[mt][nt][r]);
      }
  __syncthreads();
  int c = tid & 15, g = tid >> 4;
#pragma unroll
  for (int j = 0; j < 8; ++j) {
    int r = j * 16 + g;
    int t = m0 + r;
    size_t gb = ((size_t)t * 64 + b) * 1024 + hh * 128 + c * 8;
    *(short8*)(LO + gb) = *(const short8*)(Sh + r * 136 + c * 8);
  }
}

// =====================================================================
// K5: X[row,m] = h[row,m] + sum_n LO[row,n]*Wo[m,n]  (X fp32 = d_out)
//   fp32 stores: 16 consecutive lanes cover 64B -> already full-line.
// =====================================================================
__global__ __launch_bounds__(256, 4) void wo_gemm(const unsigned short* __restrict__ A,
                                                  const unsigned short* __restrict__ B,
                                                  const float* __restrict__ hin,
                                                  float* __restrict__ X) {
  __shared__ alignas(16) unsigned short As[128 * 64], Bs[128 * 64];
  int tid = threadIdx.x;
  int lane = tid & 63, wid = tid >> 6;
  int wm = wid >> 1, wn = wid & 1;
  int quad = lane >> 4, l16 = lane & 15;
  int m0 = blockIdx.y * 128, n0 = blockIdx.x * 128;
  const unsigned short* Ab = A + (size_t)m0 * DM_;
  const unsigned short* Bb = B + (size_t)n0 * DM_;

  floatx4 acc[4][4];
#pragma unroll
  for (int i = 0; i < 4; ++i)
#pragma unroll
    for (int j = 0; j < 4; ++j)
#pragma unroll
      for (int r = 0; r < 4; ++r) acc[i][j][r] = 0.f;

  for (int kt = 0; kt < DM_; kt += 64) {
    stage_async(Ab + kt, DM_, As, tid);
    stage_async(Bb + kt, DM_, Bs, tid);
    __syncthreads();
#pragma unroll
    for (int kk = 0; kk < 2; ++kk) {
      short8 af[4], bfv[4];
#pragma unroll
      for (int mt = 0; mt < 4; ++mt)
        af[mt] = lds_frag(As, wm * 64 + mt * 16 + l16, kk * 4 + quad);
#pragma unroll
      for (int nt = 0; nt < 4; ++nt)
        bfv[nt] = lds_frag(Bs, wn * 64 + nt * 16 + l16, kk * 4 + quad);
#pragma unroll
      for (int mt = 0; mt < 4; ++mt)
#pragma unroll
        for (int nt = 0; nt < 4; ++nt)
          acc[mt][nt] = __builtin_amdgcn_mfma_f32_16x16x32_bf16(af[mt], bfv[nt], acc[mt][nt], 0, 0, 0);
    }
    __syncthreads();
  }
#pragma unroll
  for (int mt = 0; mt < 4; ++mt)
#pragma unroll
    for (int nt = 0; nt < 4; ++nt)
#pragma unroll
      for (int r = 0; r < 4; ++r) {
        int row = m0 + wm * 64 + mt * 16 + quad * 4 + r;
        int col = n0 + wn * 64 + nt * 16 + l16;
        size_t idx = (size_t)row * DM_ + col;
        X[idx] = acc[mt][nt][r] + hin[idx];
      }
}

// =====================================================================
// K6: LayerNorm in-place on X (= d_out, fp32).  One block per row.
// =====================================================================
__global__ __launch_bounds__(256) void ln_kernel(float* __restrict__ X,
                                                 const float* __restrict__ gamma,
                                                 const float* __restrict__ beta) {
  int row = blockIdx.x;
  int tid = threadIdx.x;
  float* x = X + (size_t)row * DM_;
  float4 v = *(const float4*)(x + tid * 4);
  float s  = v.x + v.y + v.z + v.w;
  float ss = v.x * v.x + v.y * v.y + v.z * v.z + v.w * v.w;
#pragma unroll
  for (int off = 32; off; off >>= 1) {
    s  += __shfl_down(s, off);
    ss += __shfl_down(ss, off);
  }
  __shared__ float rs[4], rss[4];
  int wv = tid >> 6, lane = tid & 63;
  if (lane == 0) { rs[wv] = s; rss[wv] = ss; }
  __syncthreads();
  float St  = rs[0] + rs[1] + rs[2] + rs[3];
  float SSt = rss[0] + rss[1] + rss[2] + rss[3];
  float mu = St * (1.f / DM_);
  float var = SSt * (1.f / DM_) - mu * mu;
  float rstd = rsqrtf(var + LN_EPS_);
  float4 o;
#pragma unroll
  for (int j = 0; j < 4; ++j) {
    int c = tid * 4 + j;
    (&o.x)[j] = gamma[c] * ((&v.x)[j] - mu) * rstd + beta[c];
  }
  *(float4*)(x + tid * 4) = o;
}

// =====================================================================
extern "C" void kernel_launch(void* const* d_in, const int* in_sizes, int n_in,
                              void* d_out, int out_size, void* d_ws, size_t ws_size,
                              hipStream_t stream) {
  const float* h     = (const float*)d_in[0];
  const float* Wqkv  = (const float*)d_in[1];
  const float* Wo    = (const float*)d_in[2];
  const float* pi0   = (const float*)d_in[3];
  const float* gamma = (const float*)d_in[4];
  const float* beta  = (const float*)d_in[5];
  char* ws = (char*)d_ws;

  // ws layout (peak 194 MB, all bf16 unless noted):
  //   [0,32M)    Q(phi)      -> after scores: reused as LO [16384][1024]
  //   [32,64)    K1          [64,96) K2        [96,128) Vt
  //   [128,192)  S [512][256][256]; first 40MB aliased pre-scores by hb+Wqkvb
  //   [128,160)  hb  (bf16 h; dead before S written)
  //   [160,168)  Wqkvb       [192,194) Wob
  // X (fp32 residual) = d_out; LN in-place.
  unsigned short* QKV   = (unsigned short*)ws;
  unsigned short* Sbuf  = (unsigned short*)(ws + 134217728ull);
  unsigned short* hb    = (unsigned short*)(ws + 134217728ull);
  unsigned short* Wqkvb = (unsigned short*)(ws + 167772160ull);
  unsigned short* Wob   = (unsigned short*)(ws + 201326592ull);
  unsigned short* LO    = (unsigned short*)ws;
  float* X = (float*)d_out;

  dim3 blk(256);
  cvt_all<<<dim3(10752), blk, 0, stream>>>(h, Wqkv, Wo, hb, Wqkvb, Wob);
  qkv_gemm<<<dim3(NQKV_ / 128, ROWS_ / 128, 1), blk, 0, stream>>>(hb, Wqkvb, QKV);
  scores_kernel<<<dim3(3, 1, PAIRS_), blk, 0, stream>>>(QKV, pi0, Sbuf);
  pv_kernel<<<dim3(1, 2, PAIRS_), blk, 0, stream>>>(Sbuf, QKV + (size_t)3 * 16777216, LO);
  wo_gemm<<<dim3(DM_ / 128, ROWS_ / 128, 1), blk, 0, stream>>>(LO, Wob, h, X);
  ln_kernel<<<dim3(ROWS_, 1, 1), blk, 0, stream>>>(X, gamma, beta);
}

// Round 8
// 460.836 us; speedup vs baseline: 1.3480x; 1.0391x over previous
//
#include <hip/hip_runtime.h>

// ---- problem constants ----
#define H_     8
#define DM_    1024
#define NQKV_  4096
#define ROWS_  16384          // SLEN*BSZ = 256*64
#define PAIRS_ 512            // BSZ*H
#define SCALE_ 0.08838834764831845f
#define LN_EPS_ 1e-5f

typedef __attribute__((ext_vector_type(8))) short short8;   // 8 bf16 (4 VGPRs)
typedef __attribute__((ext_vector_type(4))) float floatx4;  // MFMA accumulator

__device__ __forceinline__ float b2f(unsigned short u) {
  union { unsigned int i; float f; } v; v.i = ((unsigned int)u) << 16; return v.f;
}
__device__ __forceinline__ unsigned short f2b(float f) {
  union { unsigned int i; float f; } v; v.f = f;
  unsigned int b = v.i;
  b += 0x7FFFu + ((b >> 16) & 1u);   // round-to-nearest-even
  return (unsigned short)(b >> 16);
}

// ---- async stage with XOR bank swizzle ----
__device__ __forceinline__ void stage_async(const unsigned short* __restrict__ g,
                                            size_t ld, unsigned short* s, int tid) {
#pragma unroll
  for (int p = 0; p < 4; ++p) {
    int idx = p * 256 + tid;
    int r = idx >> 3, j = idx & 7;
    int cg = j ^ (r & 7);
    __builtin_amdgcn_global_load_lds(
        (const __attribute__((address_space(1))) unsigned int*)(g + (size_t)r * ld + cg * 8),
        (__attribute__((address_space(3))) unsigned int*)(s + (size_t)idx * 8),
        16, 0, 0);
  }
}
__device__ __forceinline__ short8 lds_frag(const unsigned short* s, int row, int cg) {
  return *(const short8*)(s + row * 64 + ((cg ^ (row & 7)) << 3));
}

// =====================================================================
// K0: fused fp32 -> bf16 convert of h, Wqkv, Wo (8 elems/thread)
// =====================================================================
__global__ __launch_bounds__(256) void cvt_all(const float* __restrict__ h,
                                               const float* __restrict__ wq,
                                               const float* __restrict__ wo,
                                               unsigned short* __restrict__ hb,
                                               unsigned short* __restrict__ wqb,
                                               unsigned short* __restrict__ wob) {
  int i = blockIdx.x * 256 + threadIdx.x;
  const float* src; unsigned short* dst; int off;
  if (i < 2097152)      { src = h;  dst = hb;  off = i; }
  else if (i < 2621440) { src = wq; dst = wqb; off = i - 2097152; }
  else                  { src = wo; dst = wob; off = i - 2621440; }
  const float4* s4 = (const float4*)(src + (size_t)off * 8);
  float4 v0 = s4[0], v1 = s4[1];
  union { short8 v; unsigned short u[8]; } pk;
  pk.u[0] = f2b(v0.x); pk.u[1] = f2b(v0.y); pk.u[2] = f2b(v0.z); pk.u[3] = f2b(v0.w);
  pk.u[4] = f2b(v1.x); pk.u[5] = f2b(v1.y); pk.u[6] = f2b(v1.z); pk.u[7] = f2b(v1.w);
  *(short8*)(dst + (size_t)off * 8) = pk.v;
}

// =====================================================================
// K1: qkv gemm, 128x256 tile, b-major M-tiles, fused phi.
//   grid (16, 128): n0 = bx*256 covers two head-parts (q,k1) or (k2,v);
//   by: bb = by&63 (batch), lhalf = by>>6 -> M rows l in [lhalf*128,+128),
//   global row = l*64+bb.  Wave (wm,wn): wm = m-half (64 rows),
//   wn = n-half (one FULL 128-col part) -> phi row-sum is wave-local.
//   Epilogue: stage each half in LDS T[128][136]; P halves write one
//   contiguous 32KB region; V half transposed then full-line Vt stores.
// =====================================================================
__global__ __launch_bounds__(256, 2) void qkv_gemm(const unsigned short* __restrict__ A,
                                                   const unsigned short* __restrict__ B,
                                                   unsigned short* __restrict__ QKV) {
  // staging: As 8192 + Bs 16384 shorts = 48KB; epilogue: 2x T[128][136]=68KB
  __shared__ alignas(16) unsigned short Sh[34816];
  unsigned short* As = Sh;
  unsigned short* Bs = Sh + 8192;
  int tid = threadIdx.x;
  int lane = tid & 63, wid = tid >> 6;
  int wm = wid >> 1, wn = wid & 1;
  int quad = lane >> 4, l16 = lane & 15;
  int n0 = blockIdx.x * 256;
  int hh = n0 >> 9, part0 = (n0 >> 7) & 3;         // parts: (part0, part0+1)
  int bb = blockIdx.y & 63, lhalf = blockIdx.y >> 6;

  const unsigned short* Ab = A + ((size_t)(lhalf * 128) * 64 + bb) * DM_;
  const size_t lda = (size_t)64 * DM_;
  const unsigned short* Bb = B + (size_t)n0 * DM_;

  floatx4 acc[4][8];
#pragma unroll
  for (int i = 0; i < 4; ++i)
#pragma unroll
    for (int j = 0; j < 8; ++j)
#pragma unroll
      for (int r = 0; r < 4; ++r) acc[i][j][r] = 0.f;

  for (int kt = 0; kt < DM_; kt += 64) {
    stage_async(Ab + kt, lda, As, tid);
    stage_async(Bb + kt, DM_, Bs, tid);
    stage_async(Bb + (size_t)128 * DM_ + kt, DM_, Bs + 8192, tid);
    __syncthreads();
#pragma unroll
    for (int kk = 0; kk < 2; ++kk) {
      short8 af[4], bfv[8];
#pragma unroll
      for (int mt = 0; mt < 4; ++mt)
        af[mt] = lds_frag(As, wm * 64 + mt * 16 + l16, kk * 4 + quad);
#pragma unroll
      for (int nt = 0; nt < 8; ++nt)
        bfv[nt] = lds_frag(Bs, wn * 128 + nt * 16 + l16, kk * 4 + quad);
#pragma unroll
      for (int mt = 0; mt < 4; ++mt)
#pragma unroll
        for (int nt = 0; nt < 8; ++nt)
          acc[mt][nt] = __builtin_amdgcn_mfma_f32_16x16x32_bf16(af[mt], bfv[nt], acc[mt][nt], 0, 0, 0);
    }
    __syncthreads();
  }

  // ---- epilogue: each wave handles its own 128-col part ----
  int mypart = part0 + wn;
  unsigned short* T = Sh + wn * 17408;      // [128][136]
  if (mypart < 3) {
    // phi: elu+1, wave-local row-sum (8 nt x 16 l16 = all 128 cols)
    float rsum[4][4];
#pragma unroll
    for (int mt = 0; mt < 4; ++mt)
#pragma unroll
      for (int r = 0; r < 4; ++r) rsum[mt][r] = 0.f;
#pragma unroll
    for (int mt = 0; mt < 4; ++mt)
#pragma unroll
      for (int nt = 0; nt < 8; ++nt)
#pragma unroll
        for (int r = 0; r < 4; ++r) {
          float x = acc[mt][nt][r];
          float f = x > 0.f ? x + 1.f : __expf(x);
          acc[mt][nt][r] = f;
          rsum[mt][r] += f;
        }
#pragma unroll
    for (int off = 1; off < 16; off <<= 1)
#pragma unroll
      for (int mt = 0; mt < 4; ++mt)
#pragma unroll
        for (int r = 0; r < 4; ++r)
          rsum[mt][r] += __shfl_xor(rsum[mt][r], off);
#pragma unroll
    for (int mt = 0; mt < 4; ++mt)
#pragma unroll
      for (int r = 0; r < 4; ++r) {
        float inv = 1.f / rsum[mt][r];
        int rl = wm * 64 + mt * 16 + quad * 4 + r;
#pragma unroll
        for (int nt = 0; nt < 8; ++nt)
          T[rl * 136 + nt * 16 + l16] = f2b(acc[mt][nt][r] * inv);
      }
  } else {
    // V: transpose-stage T[d][l]
#pragma unroll
    for (int mt = 0; mt < 4; ++mt)
#pragma unroll
      for (int nt = 0; nt < 8; ++nt)
#pragma unroll
        for (int r = 0; r < 4; ++r) {
          int l = wm * 64 + mt * 16 + quad * 4 + r;
          int d = nt * 16 + l16;
          T[d * 136 + l] = f2b(acc[mt][nt][r]);
        }
  }
  __syncthreads();

  // ---- stores: all 256 threads, full-line per instruction ----
  int c = tid & 15, g = tid >> 4;
#pragma unroll
  for (int half = 0; half < 2; ++half) {
    int part = part0 + half;
    const unsigned short* Th = Sh + half * 17408;
    if (part < 3) {
      unsigned short* P = QKV + (size_t)part * 16777216;
      size_t base = ((size_t)((bb * 8 + hh) * 256 + lhalf * 128)) * 128;
#pragma unroll
      for (int j = 0; j < 8; ++j) {
        int rr = j * 16 + g;
        *(short8*)(P + base + rr * 128 + c * 8) = *(const short8*)(Th + rr * 136 + c * 8);
      }
    } else {
      unsigned short* Vt = QKV + (size_t)3 * 16777216;
#pragma unroll
      for (int j = 0; j < 8; ++j) {
        int d = j * 16 + g;
        size_t gb = ((size_t)((bb * 8 + hh) * 128 + d)) * 256 + lhalf * 128 + c * 8;
        *(short8*)(Vt + gb) = *(const short8*)(Th + d * 136 + c * 8);
      }
    }
  }
}

// =====================================================================
// K3: combined masked scores.  grid (3, 1, 512); full-line S stores.
// =====================================================================
__global__ __launch_bounds__(256) void scores_kernel(const unsigned short* __restrict__ QKV,
                                                     const float* __restrict__ pi0,
                                                     unsigned short* __restrict__ S) {
  __shared__ alignas(16) unsigned short Sh[24576];   // As|Bs1|Bs2; reused as T[128][136]
  __shared__ float pis[128];
  unsigned short* As  = Sh;
  unsigned short* Bs1 = Sh + 8192;
  unsigned short* Bs2 = Sh + 16384;
  int p = blockIdx.z;
  int hh = p & 7;
  int tid = threadIdx.x;
  int lane = tid & 63, wid = tid >> 6;
  int wm = wid >> 1, wn = wid & 1;
  int quad = lane >> 4, l16 = lane & 15;
  int tix = blockIdx.x;
  int m0 = (tix >= 1) ? 128 : 0;
  int n0 = (tix == 2) ? 128 : 0;
  if (tid < 128) {
    float pv = pi0[hh * 256 + m0 + tid];
    pis[tid] = fminf(fmaxf(pv, 0.f), 1.f);
  }
  const unsigned short* Qb  = QKV + (size_t)p * 32768 + (size_t)m0 * 128;
  const unsigned short* K1b = QKV + 16777216     + (size_t)p * 32768 + (size_t)n0 * 128;
  const unsigned short* K2b = QKV + 2 * 16777216 + (size_t)p * 32768 + (size_t)n0 * 128;

  floatx4 acc1[4][4], acc2[4][4];
#pragma unroll
  for (int i = 0; i < 4; ++i)
#pragma unroll
    for (int j = 0; j < 4; ++j)
#pragma unroll
      for (int r = 0; r < 4; ++r) { acc1[i][j][r] = 0.f; acc2[i][j][r] = 0.f; }

  for (int kt = 0; kt < 128; kt += 64) {
    stage_async(Qb + kt, 128, As, tid);
    stage_async(K1b + kt, 128, Bs1, tid);
    stage_async(K2b + kt, 128, Bs2, tid);
    __syncthreads();
#pragma unroll
    for (int kk = 0; kk < 2; ++kk) {
      short8 af[4], b1[4], b2v[4];
#pragma unroll
      for (int mt = 0; mt < 4; ++mt)
        af[mt] = lds_frag(As, wm * 64 + mt * 16 + l16, kk * 4 + quad);
#pragma unroll
      for (int nt = 0; nt < 4; ++nt) {
        b1[nt]  = lds_frag(Bs1, wn * 64 + nt * 16 + l16, kk * 4 + quad);
        b2v[nt] = lds_frag(Bs2, wn * 64 + nt * 16 + l16, kk * 4 + quad);
      }
#pragma unroll
      for (int mt = 0; mt < 4; ++mt)
#pragma unroll
        for (int nt = 0; nt < 4; ++nt) {
          acc1[mt][nt] = __builtin_amdgcn_mfma_f32_16x16x32_bf16(af[mt], b1[nt],  acc1[mt][nt], 0, 0, 0);
          acc2[mt][nt] = __builtin_amdgcn_mfma_f32_16x16x32_bf16(af[mt], b2v[nt], acc2[mt][nt], 0, 0, 0);
        }
    }
    __syncthreads();
  }
  // combine + mask -> T[128][136]
#pragma unroll
  for (int mt = 0; mt < 4; ++mt)
#pragma unroll
    for (int nt = 0; nt < 4; ++nt)
#pragma unroll
      for (int r = 0; r < 4; ++r) {
        int tl = wm * 64 + mt * 16 + quad * 4 + r;
        int sl = wn * 64 + nt * 16 + l16;
        float pv = pis[tl];
        float v = (n0 + sl <= m0 + tl) ? (pv * acc1[mt][nt][r] + (1.f - pv) * acc2[mt][nt][r]) : 0.f;
        Sh[tl * 136 + sl] = f2b(v);
      }
  __syncthreads();
  int c = tid & 15, g = tid >> 4;
#pragma unroll
  for (int j = 0; j < 8; ++j) {
    int r = j * 16 + g;
    size_t gb = (size_t)p * 65536 + (size_t)(m0 + r) * 256 + n0 + c * 8;
    *(short8*)(S + gb) = *(const short8*)(Sh + r * 136 + c * 8);
  }
}

// =====================================================================
// K4: O = SCALE * S @ V -> LO; full-line stores.  grid (1,2,512)
// =====================================================================
__global__ __launch_bounds__(256, 4) void pv_kernel(const unsigned short* __restrict__ S,
                                                    const unsigned short* __restrict__ Vt,
                                                    unsigned short* __restrict__ LO) {
  __shared__ alignas(16) unsigned short Sh[17408];   // As|Bs; reused as T[128][136]
  unsigned short* As = Sh;
  unsigned short* Bs = Sh + 8192;
  int p = blockIdx.z;
  int b = p >> 3, hh = p & 7;
  int tid = threadIdx.x;
  int lane = tid & 63, wid = tid >> 6;
  int wm = wid >> 1, wn = wid & 1;
  int quad = lane >> 4, l16 = lane & 15;
  int m0 = blockIdx.y * 128;
  int kEnd = (blockIdx.y == 0) ? 128 : 256;   // rows t<128 only need s<128
  const unsigned short* Ab = S  + (size_t)p * 65536 + (size_t)m0 * 256;
  const unsigned short* Bb = Vt + (size_t)p * 32768;

  floatx4 acc[4][4];
#pragma unroll
  for (int i = 0; i < 4; ++i)
#pragma unroll
    for (int j = 0; j < 4; ++j)
#pragma unroll
      for (int r = 0; r < 4; ++r) acc[i][j][r] = 0.f;

  for (int kt = 0; kt < kEnd; kt += 64) {
    stage_async(Ab + kt, 256, As, tid);
    stage_async(Bb + kt, 256, Bs, tid);
    __syncthreads();
#pragma unroll
    for (int kk = 0; kk < 2; ++kk) {
      short8 af[4], bfv[4];
#pragma unroll
      for (int mt = 0; mt < 4; ++mt)
        af[mt] = lds_frag(As, wm * 64 + mt * 16 + l16, kk * 4 + quad);
#pragma unroll
      for (int nt = 0; nt < 4; ++nt)
        bfv[nt] = lds_frag(Bs, wn * 64 + nt * 16 + l16, kk * 4 + quad);
#pragma unroll
      for (int mt = 0; mt < 4; ++mt)
#pragma unroll
        for (int nt = 0; nt < 4; ++nt)
          acc[mt][nt] = __builtin_amdgcn_mfma_f32_16x16x32_bf16(af[mt], bfv[nt], acc[mt][nt], 0, 0, 0);
    }
    __syncthreads();
  }
  // stage scaled O into T[128][136]
#pragma unroll
  for (int mt = 0; mt < 4; ++mt)
#pragma unroll
    for (int nt = 0; nt < 4; ++nt)
#pragma unroll
      for (int r = 0; r < 4; ++r) {
        int tl = wm * 64 + mt * 16 + quad * 4 + r;
        int d = wn * 64 + nt * 16 + l16;
        Sh[tl * 136 + d] = f2b(SCALE_ * acc[mt][nt][r]);
      }
  __syncthreads();
  int c = tid & 15, g = tid >> 4;
#pragma unroll
  for (int j = 0; j < 8; ++j) {
    int r = j * 16 + g;
    int t = m0 + r;
    size_t gb = ((size_t)t * 64 + b) * 1024 + hh * 128 + c * 8;
    *(short8*)(LO + gb) = *(const short8*)(Sh + r * 136 + c * 8);
  }
}

// =====================================================================
// K5: X[row,m] = h[row,m] + sum_n LO[row,n]*Wo[m,n]  (X fp32 = d_out)
// =====================================================================
__global__ __launch_bounds__(256, 4) void wo_gemm(const unsigned short* __restrict__ A,
                                                  const unsigned short* __restrict__ B,
                                                  const float* __restrict__ hin,
                                                  float* __restrict__ X) {
  __shared__ alignas(16) unsigned short As[128 * 64], Bs[128 * 64];
  int tid = threadIdx.x;
  int lane = tid & 63, wid = tid >> 6;
  int wm = wid >> 1, wn = wid & 1;
  int quad = lane >> 4, l16 = lane & 15;
  int m0 = blockIdx.y * 128, n0 = blockIdx.x * 128;
  const unsigned short* Ab = A + (size_t)m0 * DM_;
  const unsigned short* Bb = B + (size_t)n0 * DM_;

  floatx4 acc[4][4];
#pragma unroll
  for (int i = 0; i < 4; ++i)
#pragma unroll
    for (int j = 0; j < 4; ++j)
#pragma unroll
      for (int r = 0; r < 4; ++r) acc[i][j][r] = 0.f;

  for (int kt = 0; kt < DM_; kt += 64) {
    stage_async(Ab + kt, DM_, As, tid);
    stage_async(Bb + kt, DM_, Bs, tid);
    __syncthreads();
#pragma unroll
    for (int kk = 0; kk < 2; ++kk) {
      short8 af[4], bfv[4];
#pragma unroll
      for (int mt = 0; mt < 4; ++mt)
        af[mt] = lds_frag(As, wm * 64 + mt * 16 + l16, kk * 4 + quad);
#pragma unroll
      for (int nt = 0; nt < 4; ++nt)
        bfv[nt] = lds_frag(Bs, wn * 64 + nt * 16 + l16, kk * 4 + quad);
#pragma unroll
      for (int mt = 0; mt < 4; ++mt)
#pragma unroll
        for (int nt = 0; nt < 4; ++nt)
          acc[mt][nt] = __builtin_amdgcn_mfma_f32_16x16x32_bf16(af[mt], bfv[nt], acc[mt][nt], 0, 0, 0);
    }
    __syncthreads();
  }
#pragma unroll
  for (int mt = 0; mt < 4; ++mt)
#pragma unroll
    for (int nt = 0; nt < 4; ++nt)
#pragma unroll
      for (int r = 0; r < 4; ++r) {
        int row = m0 + wm * 64 + mt * 16 + quad * 4 + r;
        int col = n0 + wn * 64 + nt * 16 + l16;
        size_t idx = (size_t)row * DM_ + col;
        X[idx] = acc[mt][nt][r] + hin[idx];
      }
}

// =====================================================================
// K6: LayerNorm in-place on X (= d_out, fp32).  One block per row.
// =====================================================================
__global__ __launch_bounds__(256) void ln_kernel(float* __restrict__ X,
                                                 const float* __restrict__ gamma,
                                                 const float* __restrict__ beta) {
  int row = blockIdx.x;
  int tid = threadIdx.x;
  float* x = X + (size_t)row * DM_;
  float4 v = *(const float4*)(x + tid * 4);
  float s  = v.x + v.y + v.z + v.w;
  float ss = v.x * v.x + v.y * v.y + v.z * v.z + v.w * v.w;
#pragma unroll
  for (int off = 32; off; off >>= 1) {
    s  += __shfl_down(s, off);
    ss += __shfl_down(ss, off);
  }
  __shared__ float rs[4], rss[4];
  int wv = tid >> 6, lane = tid & 63;
  if (lane == 0) { rs[wv] = s; rss[wv] = ss; }
  __syncthreads();
  float St  = rs[0] + rs[1] + rs[2] + rs[3];
  float SSt = rss[0] + rss[1] + rss[2] + rss[3];
  float mu = St * (1.f / DM_);
  float var = SSt * (1.f / DM_) - mu * mu;
  float rstd = rsqrtf(var + LN_EPS_);
  float4 o;
#pragma unroll
  for (int j = 0; j < 4; ++j) {
    int c = tid * 4 + j;
    (&o.x)[j] = gamma[c] * ((&v.x)[j] - mu) * rstd + beta[c];
  }
  *(float4*)(x + tid * 4) = o;
}

// =====================================================================
extern "C" void kernel_launch(void* const* d_in, const int* in_sizes, int n_in,
                              void* d_out, int out_size, void* d_ws, size_t ws_size,
                              hipStream_t stream) {
  const float* h     = (const float*)d_in[0];
  const float* Wqkv  = (const float*)d_in[1];
  const float* Wo    = (const float*)d_in[2];
  const float* pi0   = (const float*)d_in[3];
  const float* gamma = (const float*)d_in[4];
  const float* beta  = (const float*)d_in[5];
  char* ws = (char*)d_ws;

  unsigned short* QKV   = (unsigned short*)ws;
  unsigned short* Sbuf  = (unsigned short*)(ws + 134217728ull);
  unsigned short* hb    = (unsigned short*)(ws + 134217728ull);
  unsigned short* Wqkvb = (unsigned short*)(ws + 167772160ull);
  unsigned short* Wob   = (unsigned short*)(ws + 201326592ull);
  unsigned short* LO    = (unsigned short*)ws;
  float* X = (float*)d_out;

  dim3 blk(256);
  cvt_all<<<dim3(10752), blk, 0, stream>>>(h, Wqkv, Wo, hb, Wqkvb, Wob);
  qkv_gemm<<<dim3(NQKV_ / 256, ROWS_ / 128, 1), blk, 0, stream>>>(hb, Wqkvb, QKV);
  scores_kernel<<<dim3(3, 1, PAIRS_), blk, 0, stream>>>(QKV, pi0, Sbuf);
  pv_kernel<<<dim3(1, 2, PAIRS_), blk, 0, stream>>>(Sbuf, QKV + (size_t)3 * 16777216, LO);
  wo_gemm<<<dim3(DM_ / 128, ROWS_ / 128, 1), blk, 0, stream>>>(LO, Wob, h, X);
  ln_kernel<<<dim3(ROWS_, 1, 1), blk, 0, stream>>>(X, gamma, beta);
}